// Round 6
// baseline (12821.434 us; speedup 1.0000x reference)
//
#include <hip/hip_runtime.h>
#include <math.h>

#define T_SEQ 2048
#define HID   64
#define CH    4
#define NCH   (T_SEQ / CH)     // 512 chunks
#define KMAX  (NCH + 10)       // last: layer 4, chunk 511 at k = 511 + 2*4 + 2 = 521

typedef __attribute__((ext_vector_type(2))) float f32x2;
typedef __attribute__((ext_vector_type(4))) float f32x4;

__device__ __forceinline__ float sigmoid_(float x) {
    return 1.0f / (1.0f + __expf(-x));
}
__device__ __forceinline__ float tanh_(float x) {
    float e = __expf(2.0f * x);
    return 1.0f - 2.0f / (e + 1.0f);
}

// All 5 LSTM layers, wavefront-pipelined in ONE kernel.
// grid = 256 blocks (1 sample), block = 768 threads (12 waves, 3/SIMD):
//   waves 0-4  ("R"): recurrence for layer l=wave. lane j owns hidden unit j.
//                     i,f,o W_hh rows in VGPRs (192 regs, shared array with G
//                     waves' weights -- union, so regalloc doesn't sum the
//                     branches); g rows in LDS. At supercycle k, R_l runs
//                     chunk c = k-2l-2 (4 steps, barrier-free internally).
//   waves 5-11 ("G"): xg = in @ W_ih^T + b for all 5 layers. 1280 gate rows
//                     flat-distributed, 3 row-slots/lane, weights in the same
//                     union register array. At k, slot of layer l computes
//                     chunk c = k-2l-1 from h_if[l] (written by R_{l-1} at
//                     k-1; h_if[0] = x staged by wave 5 at k-1).
// One __syncthreads per supercycle. Schedule (all single-buffer safe, verified
// parity/order): stage x chunk c at k=c -> GEMM_0 at k=c+1 -> R_0 at k=c+2 ->
// GEMM_1 at k=c+3 -> ... -> R_4 at k=c+10.
// Intermediate h never touches HBM; only layer-4 last-step h is written.
__global__ __launch_bounds__(768)
void lstm_fused_kernel(const float* __restrict__ x,         // [256,2048,45]
                       const float* __restrict__ W_ih0,     // [256,45]
                       const float* __restrict__ W_ih_rest, // [4,256,64]
                       const float* __restrict__ W_hh,      // [5,256,64]
                       const float* __restrict__ b_ih,      // [5,256]
                       const float* __restrict__ b_hh,      // [5,256]
                       float* __restrict__ h_last)          // [256,64] (d_ws)
{
    __shared__ float s_xg[2][5][CH][256];    // 40 KB  xg double buffer
    __shared__ float s_wg[5][16][64][4];     // 80 KB  g-gate W_hh rows
    __shared__ float s_hif[5][2][CH][64];    // 10 KB  layer-input chunks (hif[0]=x, 64-padded)
    __shared__ float s_h[5][64];             // 1.25KB current h per layer
    // total 131.25 KB -> 1 block/CU, 12 waves = 3/SIMD

    const int tid  = threadIdx.x;
    const int wave = tid >> 6;
    const int lane = tid & 63;
    const int s    = blockIdx.x;

    // ---- zero x padding rows (cols 45..63 stay 0 forever) and h0 ----
    {
        float* z = &s_hif[0][0][0][0];
        for (int i = tid; i < 2 * CH * HID; i += 768) z[i] = 0.0f;
        if (tid < 5 * HID) (&s_h[0][0])[tid] = 0.0f;
    }

    // ---- union weight register file: R uses [0..47] = wi|wf|wo rows;
    //      G uses [0..47] = 3 slots x 16 of W_ih rows ----
    f32x4 wreg[48];
    float gbias[3];
    int   glayer[3] = {0, 0, 0}, grow[3] = {0, 0, 0}, gvalid[3] = {0, 0, 0};
    float cc = 0.0f;   // cell state (R waves)

    if (wave < 5) {
        const float* Wl = W_hh + (size_t)wave * 256 * HID;
#pragma unroll
        for (int k4 = 0; k4 < 16; ++k4) {
            wreg[k4]      = *reinterpret_cast<const f32x4*>(&Wl[(size_t)(lane)       * HID + 4 * k4]);
            wreg[16 + k4] = *reinterpret_cast<const f32x4*>(&Wl[(size_t)(64  + lane) * HID + 4 * k4]);
            wreg[32 + k4] = *reinterpret_cast<const f32x4*>(&Wl[(size_t)(192 + lane) * HID + 4 * k4]);
        }
#pragma unroll
        for (int k4 = 0; k4 < 16; ++k4) {
            *reinterpret_cast<float4*>(&s_wg[wave][k4][lane][0]) =
                *reinterpret_cast<const float4*>(&Wl[(size_t)(128 + lane) * HID + 4 * k4]);
        }
    } else {
        const int flat = (wave - 5) * 64 + lane;    // 0..447
#pragma unroll
        for (int s3 = 0; s3 < 3; ++s3) {
            const int idx = s3 * 448 + flat;        // flat (layer,row)
            gvalid[s3] = (idx < 1280);
            const int ly = idx >> 8, row = idx & 255;
            glayer[s3] = ly;
            grow[s3]   = row;
            if (gvalid[s3]) {
                for (int k4 = 0; k4 < 16; ++k4) {
                    float tmp[4];
                    for (int j = 0; j < 4; ++j) {
                        const int kk = 4 * k4 + j;
                        tmp[j] = (ly == 0)
                                   ? (kk < 45 ? W_ih0[(size_t)row * 45 + kk] : 0.0f)
                                   : W_ih_rest[(((size_t)(ly - 1) * 256 + row) * HID) + kk];
                    }
                    f32x4 v = {tmp[0], tmp[1], tmp[2], tmp[3]};
                    wreg[s3 * 16 + k4] = v;
                }
                gbias[s3] = b_ih[ly * 256 + row] + b_hh[ly * 256 + row];
            } else {
                gbias[s3] = 0.0f;
            }
        }
    }
    __syncthreads();

    const float* x_s = x + (size_t)s * T_SEQ * 45;

    // ---- supercycle loop ----
    for (int k = 0; k < KMAX; ++k) {
        if (wave >= 5) {
            // -- wave 5: stage x chunk k (read at k+1 by GEMM_0) --
            if (wave == 5 && k < NCH) {
                const int buf = k & 1;
                float* dst = &s_hif[0][buf][0][0];        // [CH][64], rows 45..63 stay 0
#pragma unroll
                for (int r = 0; r < 3; ++r) {
                    const int i = lane + 64 * r;          // 0..179 = t*45+d
                    if (i < CH * 45) {
                        const int t = i / 45, d = i - t * 45;
                        dst[t * HID + d] = x_s[(size_t)k * (CH * 45) + i];
                    }
                }
            }
            // -- GEMM slots --
#pragma unroll
            for (int s3 = 0; s3 < 3; ++s3) {
                if (gvalid[s3]) {
                    const int ly = glayer[s3];
                    const int c  = k - 2 * ly - 1;
                    if (c >= 0 && c < NCH) {
                        const int buf = c & 1;
#pragma unroll
                        for (int t = 0; t < CH; ++t) {
                            f32x4 a = {0.0f, 0.0f, 0.0f, 0.0f};
#pragma unroll
                            for (int k4 = 0; k4 < 16; ++k4) {
                                f32x4 h4 = *reinterpret_cast<const f32x4*>(&s_hif[ly][buf][t][4 * k4]);
                                a += wreg[s3 * 16 + k4] * h4;
                            }
                            s_xg[buf][ly][t][grow[s3]] = gbias[s3] + ((a.x + a.y) + (a.z + a.w));
                        }
                    }
                }
            }
        } else {
            // -- recurrence: layer l = wave, chunk c --
            const int l = wave;
            const int c = k - 2 * l - 2;
            if (c >= 0 && c < NCH) {
                const int buf = c & 1;
#pragma unroll
                for (int t = 0; t < CH; ++t) {
                    const float xi = s_xg[buf][l][t][lane];
                    const float xf = s_xg[buf][l][t][64 + lane];
                    const float xg = s_xg[buf][l][t][128 + lane];
                    const float xo = s_xg[buf][l][t][192 + lane];

                    f32x4 ai = {0, 0, 0, 0}, af = {0, 0, 0, 0};
                    f32x4 ag = {0, 0, 0, 0}, ao = {0, 0, 0, 0};
#pragma unroll
                    for (int k4 = 0; k4 < 16; ++k4) {
                        f32x4 h4  = *reinterpret_cast<const f32x4*>(&s_h[l][4 * k4]);       // uniform bcast
                        f32x4 wg4 = *reinterpret_cast<const f32x4*>(&s_wg[l][k4][lane][0]); // per-lane
                        ai += wreg[k4]      * h4;
                        af += wreg[16 + k4] * h4;
                        ao += wreg[32 + k4] * h4;
                        ag += wg4 * h4;
                    }
                    const float pi = xi + ((ai.x + ai.y) + (ai.z + ai.w));
                    const float pf = xf + ((af.x + af.y) + (af.z + af.w));
                    const float pg = xg + ((ag.x + ag.y) + (ag.z + ag.w));
                    const float po = xo + ((ao.x + ao.y) + (ao.z + ao.w));

                    const float I = sigmoid_(pi);
                    const float F = sigmoid_(pf);
                    const float G = tanh_(pg);
                    const float O = sigmoid_(po);
                    cc = fmaf(F, cc, I * G);
                    const float h = O * tanh_(cc);

                    s_h[l][lane] = h;                       // next-step bcast (same wave, in-order)
                    if (l < 4) {
                        s_hif[l + 1][buf][t][lane] = h;     // next layer's GEMM input
                    } else if (c == NCH - 1 && t == CH - 1) {
                        h_last[(size_t)s * HID + lane] = h; // only global h write
                    }
                }
            }
        }
        __syncthreads();
    }
}

// MLP head: features = gelu(last @ Wl^T + bl); out = relu(features @ Wo^T + bo)
// d_out layout: out[256*4] first, then features[256*128].
__global__ __launch_bounds__(128)
void head_kernel(const float* __restrict__ h_last,  // [256, 64]
                 const float* __restrict__ Wl,      // [128, 64]
                 const float* __restrict__ bl,      // [128]
                 const float* __restrict__ Wo,      // [4, 128]
                 const float* __restrict__ bo,      // [4]
                 float* __restrict__ d_out)
{
    __shared__ float s_last[HID];
    __shared__ float s_feat[128];
    const int s = blockIdx.x;
    const int j = threadIdx.x;

    if (j < HID) s_last[j] = h_last[(size_t)s * HID + j];
    __syncthreads();

    float acc = bl[j];
#pragma unroll
    for (int k = 0; k < HID; ++k)
        acc = fmaf(s_last[k], Wl[j * HID + k], acc);
    float f = 0.5f * acc * (1.0f + erff(acc * 0.70710678118654752440f));
    d_out[256 * 4 + s * 128 + j] = f;
    s_feat[j] = f;
    __syncthreads();

    if (j < 4) {
        float a = bo[j];
#pragma unroll
        for (int k = 0; k < 128; ++k)
            a = fmaf(s_feat[k], Wo[j * 128 + k], a);
        d_out[s * 4 + j] = fmaxf(a, 0.0f);
    }
}

extern "C" void kernel_launch(void* const* d_in, const int* in_sizes, int n_in,
                              void* d_out, int out_size, void* d_ws, size_t ws_size,
                              hipStream_t stream)
{
    const float* x         = (const float*)d_in[0];  // [256, 2048, 45]
    const float* W_ih0     = (const float*)d_in[1];  // [256, 45]
    const float* W_ih_rest = (const float*)d_in[2];  // [4, 256, 64]
    const float* W_hh      = (const float*)d_in[3];  // [5, 256, 64]
    const float* b_ih      = (const float*)d_in[4];  // [5, 256]
    const float* b_hh      = (const float*)d_in[5];  // [5, 256]
    const float* Wl        = (const float*)d_in[6];  // [128, 64]
    const float* bl        = (const float*)d_in[7];  // [128]
    const float* Wo        = (const float*)d_in[8];  // [4, 128]
    const float* bo        = (const float*)d_in[9];  // [4]

    float* h_last = (float*)d_ws;   // [256, 64] fp32

    lstm_fused_kernel<<<256, 768, 0, stream>>>(
        x, W_ih0, W_ih_rest, W_hh, b_ih, b_hh, h_last);
    head_kernel<<<256, 128, 0, stream>>>(h_last, Wl, bl, Wo, bo, (float*)d_out);
}